// Round 1
// baseline (68.812 us; speedup 1.0000x reference)
//
#include <hip/hip_runtime.h>

// GetScalars: per-atom SO(3)-invariant Gram features.
// out[b][a][:] = concat( part0[b][a][0][0][:],                      // 32
//                        gram_l(part_l)  for l in 0..3 )            // 4 * 32*32
// gram_l[c][d] = sum_m part_l[b][a][0][m][c] * part_l[b][a][0][m][d]
//
// Memory-bound: 33.5 MB read + 270.5 MB write => ~48us floor @ 6.3 TB/s.

constexpr int C = 32;
constexpr int OUT_PER_ATOM = C + 4 * C * C;   // 4128 floats
constexpr int ROWS = 16;                      // 1 + 3 + 5 + 7 m-rows total
constexpr int NQ = OUT_PER_ATOM / 4;          // 1032 float4 per atom

__global__ __launch_bounds__(256) void getscalars_kernel(
    const float* __restrict__ p0, const float* __restrict__ p1,
    const float* __restrict__ p2, const float* __restrict__ p3,
    float* __restrict__ out)
{
    // LDS layout: row r (0..15) holds one m-row of 32 channels.
    // rows: [0]=l0, [1..3]=l1, [4..8]=l2, [9..15]=l3  (row base = l*l)
    __shared__ float lds[ROWS * C];

    const int atom = blockIdx.x;          // 0 .. B*NATOMS-1
    const int t = threadIdx.x;            // 0 .. 255

    const float* s0 = p0 + (size_t)atom * (1 * C);
    const float* s1 = p1 + (size_t)atom * (3 * C);
    const float* s2 = p2 + (size_t)atom * (5 * C);
    const float* s3 = p3 + (size_t)atom * (7 * C);

    // Stage 512 floats (2 KB) into LDS, coalesced.
    for (int i = t; i < ROWS * C; i += 256) {
        const int row = i >> 5;
        const int col = i & 31;
        float v;
        if (row < 1)      v = s0[col];
        else if (row < 4) v = s1[(row - 1) * C + col];
        else if (row < 9) v = s2[(row - 4) * C + col];
        else              v = s3[(row - 9) * C + col];
        lds[i] = v;
    }
    __syncthreads();

    float4* o4 = reinterpret_cast<float4*>(out + (size_t)atom * OUT_PER_ATOM);

    for (int q = t; q < NQ; q += 256) {
        float4 r;
        if (q < C / 4) {
            // scalars_part0 copy
            r.x = lds[4 * q + 0];
            r.y = lds[4 * q + 1];
            r.z = lds[4 * q + 2];
            r.w = lds[4 * q + 3];
        } else {
            const int jj  = 4 * q - C;        // 0 .. 4095 within gram blocks
            const int l   = jj >> 10;         // which gram (1024 entries each)
            const int rem = jj & 1023;
            const int c   = rem >> 5;         // row of gram
            const int d   = rem & 31;         // col of gram (multiple of 4)
            const int row0 = l * l;           // LDS row base: 0,1,4,9
            const int nm   = 2 * l + 1;       // 1,3,5,7

            float a0 = 0.f, a1 = 0.f, a2 = 0.f, a3 = 0.f;
            for (int m = 0; m < nm; ++m) {
                const float* rowp = &lds[(row0 + m) * C];
                const float pc = rowp[c];
                a0 += pc * rowp[d + 0];
                a1 += pc * rowp[d + 1];
                a2 += pc * rowp[d + 2];
                a3 += pc * rowp[d + 3];
            }
            r.x = a0; r.y = a1; r.z = a2; r.w = a3;
        }
        o4[q] = r;
    }
}

extern "C" void kernel_launch(void* const* d_in, const int* in_sizes, int n_in,
                              void* d_out, int out_size, void* d_ws, size_t ws_size,
                              hipStream_t stream) {
    const float* p0 = (const float*)d_in[0];
    const float* p1 = (const float*)d_in[1];
    const float* p2 = (const float*)d_in[2];
    const float* p3 = (const float*)d_in[3];
    float* out = (float*)d_out;

    const int natoms = in_sizes[0] / C;   // B * NUM_ATOMS = 16384
    getscalars_kernel<<<natoms, 256, 0, stream>>>(p0, p1, p2, p3, out);
}

// Round 3
// 64.981 us; speedup vs baseline: 1.0590x; 1.0590x over previous
//
#include <hip/hip_runtime.h>

// GetScalars: per-atom SO(3)-invariant Gram features.
// out[b][a][:] = concat( part0[b][a][0][0][:],                      // 32
//                        gram_l(part_l)  for l in 0..3 )            // 4 * 32*32
// gram_l[c][d] = sum_m part_l[b][a][0][m][c] * part_l[b][a][0][m][d]
//
// Memory-bound: 33.5 MB read + 270.5 MB write => ~48us floor @ 6.3 TB/s.
//
// Structure: 1 block (256 thr) per atom. Thread t owns (c = t>>3, d = (t&7)*4)
// and computes that float4 of ALL four grams -> every loop compile-time,
// LDS reads batched & broadcast (conflict-free), stores float4 coalesced.
//
// Staging quad counts per l: 8 / 24 / 40 / 56  (sum = 128 float4 = 512 floats)
// -> thread ranges [0,8) [8,32) [32,72) [72,128).  (Round-2 bug: wrong splits
// caused OOB read of p3 and scrambled LDS.)

constexpr int C = 32;
constexpr int OUT_PER_ATOM = C + 4 * C * C;   // 4128 floats

__global__ __launch_bounds__(256) void getscalars_kernel(
    const float* __restrict__ p0, const float* __restrict__ p1,
    const float* __restrict__ p2, const float* __restrict__ p3,
    float* __restrict__ out)
{
    // LDS rows 0..15 = m-rows: [0]=l0, [1..3]=l1, [4..8]=l2, [9..15]=l3
    __shared__ float lds[16 * C];

    const int atom = blockIdx.x;
    const int t = threadIdx.x;

    // Stage 512 floats = 128 float4 (all per-atom bases 16B-aligned).
    if (t < 128) {
        const float4* src;
        int idx;
        if (t < 8)       { src = (const float4*)(p0 + (size_t)atom * 32);  idx = t; }
        else if (t < 32) { src = (const float4*)(p1 + (size_t)atom * 96);  idx = t - 8; }
        else if (t < 72) { src = (const float4*)(p2 + (size_t)atom * 160); idx = t - 32; }
        else             { src = (const float4*)(p3 + (size_t)atom * 224); idx = t - 72; }
        reinterpret_cast<float4*>(lds)[t] = src[idx];
    }
    __syncthreads();

    const int c = t >> 3;         // 0..31
    const int d = (t & 7) * 4;    // 0,4,...,28

    // Batch-load all 16 rows: pc (scalar at col c), pd (float4 at cols d..d+3).
    float  pc[16];
    float4 pd[16];
    #pragma unroll
    for (int r = 0; r < 16; ++r) {
        pc[r] = lds[r * C + c];
        pd[r] = *reinterpret_cast<const float4*>(&lds[r * C + d]);
    }

    float* outp = out + (size_t)atom * OUT_PER_ATOM;

    // scalars_part0: first 32 floats = lds row 0
    if (t < 8) {
        reinterpret_cast<float4*>(outp)[t] = reinterpret_cast<const float4*>(lds)[t];
    }

    float4 g;
    // gram l=0: row 0
    g.x = pc[0] * pd[0].x;
    g.y = pc[0] * pd[0].y;
    g.z = pc[0] * pd[0].z;
    g.w = pc[0] * pd[0].w;
    *reinterpret_cast<float4*>(outp + C + 0 * 1024 + 4 * t) = g;

    // gram l=1: rows 1..3
    g.x = pc[1] * pd[1].x; g.y = pc[1] * pd[1].y; g.z = pc[1] * pd[1].z; g.w = pc[1] * pd[1].w;
    #pragma unroll
    for (int r = 2; r <= 3; ++r) {
        g.x += pc[r] * pd[r].x; g.y += pc[r] * pd[r].y;
        g.z += pc[r] * pd[r].z; g.w += pc[r] * pd[r].w;
    }
    *reinterpret_cast<float4*>(outp + C + 1 * 1024 + 4 * t) = g;

    // gram l=2: rows 4..8
    g.x = pc[4] * pd[4].x; g.y = pc[4] * pd[4].y; g.z = pc[4] * pd[4].z; g.w = pc[4] * pd[4].w;
    #pragma unroll
    for (int r = 5; r <= 8; ++r) {
        g.x += pc[r] * pd[r].x; g.y += pc[r] * pd[r].y;
        g.z += pc[r] * pd[r].z; g.w += pc[r] * pd[r].w;
    }
    *reinterpret_cast<float4*>(outp + C + 2 * 1024 + 4 * t) = g;

    // gram l=3: rows 9..15
    g.x = pc[9] * pd[9].x; g.y = pc[9] * pd[9].y; g.z = pc[9] * pd[9].z; g.w = pc[9] * pd[9].w;
    #pragma unroll
    for (int r = 10; r <= 15; ++r) {
        g.x += pc[r] * pd[r].x; g.y += pc[r] * pd[r].y;
        g.z += pc[r] * pd[r].z; g.w += pc[r] * pd[r].w;
    }
    *reinterpret_cast<float4*>(outp + C + 3 * 1024 + 4 * t) = g;
}

extern "C" void kernel_launch(void* const* d_in, const int* in_sizes, int n_in,
                              void* d_out, int out_size, void* d_ws, size_t ws_size,
                              hipStream_t stream) {
    const float* p0 = (const float*)d_in[0];
    const float* p1 = (const float*)d_in[1];
    const float* p2 = (const float*)d_in[2];
    const float* p3 = (const float*)d_in[3];
    float* out = (float*)d_out;

    const int natoms = in_sizes[0] / C;   // B * NUM_ATOMS = 16384
    getscalars_kernel<<<natoms, 256, 0, stream>>>(p0, p1, p2, p3, out);
}

// Round 4
// 58.168 us; speedup vs baseline: 1.1830x; 1.1171x over previous
//
#include <hip/hip_runtime.h>

// GetScalars: per-atom SO(3)-invariant Gram features.
// out[b][a][:] = concat( part0 scalars (32), gram_l for l=0..3 (4*1024) )
// gram_l[c][d] = sum_m part_l[..m..][c] * part_l[..m..][d]
//
// Memory-bound: 33.5 MB read + 270.5 MB write. Fill kernels hit 6.6 TB/s
// pure-write; mixed R/W floor ~53 us.
//
// R4 structure: 4 atoms / 256-thread block (4096 blocks).
//  - staging: 512 float4 = exactly 2 per thread, ONE barrier per 4 atoms
//  - per-thread (c = t>>3, d = (t&7)*4), per-l templated compute keeps
//    <=7 rows live -> low VGPR -> higher occupancy to hide load latency.

constexpr int C = 32;
constexpr int OUT_PER_ATOM = C + 4 * C * C;   // 4128 floats
constexpr int APB = 4;                        // atoms per block

// gram float4 for rows [R0, R0+NM) at (c, d..d+3)
template <int R0, int NM>
__device__ __forceinline__ float4 gram4(const float* __restrict__ L, int c, int d) {
    float ax = 0.f, ay = 0.f, az = 0.f, aw = 0.f;
    #pragma unroll
    for (int m = 0; m < NM; ++m) {
        const float* row = L + (R0 + m) * C;
        const float pc = row[c];
        const float4 pd = *reinterpret_cast<const float4*>(row + d);
        ax += pc * pd.x; ay += pc * pd.y; az += pc * pd.z; aw += pc * pd.w;
    }
    return make_float4(ax, ay, az, aw);
}

__global__ __launch_bounds__(256) void getscalars_kernel(
    const float* __restrict__ p0, const float* __restrict__ p1,
    const float* __restrict__ p2, const float* __restrict__ p3,
    float* __restrict__ out)
{
    // per atom: rows 0..15 = m-rows ([0]=l0, [1..3]=l1, [4..8]=l2, [9..15]=l3)
    __shared__ float lds[APB * 16 * C];   // 8 KB

    const int t = threadIdx.x;
    const int atom0 = blockIdx.x * APB;

    // Stage 4 atoms: 512 float4, 2 per thread, coalesced per input array.
    #pragma unroll
    for (int s = 0; s < 2; ++s) {
        const int j = t + s * 256;        // 0..511 global quad in block
        const int a = j >> 7;             // atom within block
        const int k = j & 127;            // quad within atom (8/24/40/56 split)
        const int atom = atom0 + a;
        const float4* src;
        int idx;
        if (k < 8)       { src = (const float4*)(p0 + (size_t)atom * 32);  idx = k; }
        else if (k < 32) { src = (const float4*)(p1 + (size_t)atom * 96);  idx = k - 8; }
        else if (k < 72) { src = (const float4*)(p2 + (size_t)atom * 160); idx = k - 32; }
        else             { src = (const float4*)(p3 + (size_t)atom * 224); idx = k - 72; }
        reinterpret_cast<float4*>(lds)[j] = src[idx];
    }
    __syncthreads();

    const int c = t >> 3;         // 0..31
    const int d = (t & 7) * 4;    // 0,4,...,28

    for (int a = 0; a < APB; ++a) {
        const float* L = lds + a * 16 * C;
        float* outp = out + (size_t)(atom0 + a) * OUT_PER_ATOM;

        // scalars_part0: first 32 floats = row 0
        if (t < 8) {
            reinterpret_cast<float4*>(outp)[t] =
                reinterpret_cast<const float4*>(L)[t];
        }

        *reinterpret_cast<float4*>(outp + C + 0 * 1024 + 4 * t) = gram4<0, 1>(L, c, d);
        *reinterpret_cast<float4*>(outp + C + 1 * 1024 + 4 * t) = gram4<1, 3>(L, c, d);
        *reinterpret_cast<float4*>(outp + C + 2 * 1024 + 4 * t) = gram4<4, 5>(L, c, d);
        *reinterpret_cast<float4*>(outp + C + 3 * 1024 + 4 * t) = gram4<9, 7>(L, c, d);
    }
}

extern "C" void kernel_launch(void* const* d_in, const int* in_sizes, int n_in,
                              void* d_out, int out_size, void* d_ws, size_t ws_size,
                              hipStream_t stream) {
    const float* p0 = (const float*)d_in[0];
    const float* p1 = (const float*)d_in[1];
    const float* p2 = (const float*)d_in[2];
    const float* p3 = (const float*)d_in[3];
    float* out = (float*)d_out;

    const int natoms = in_sizes[0] / C;   // B * NUM_ATOMS = 16384
    getscalars_kernel<<<natoms / APB, 256, 0, stream>>>(p0, p1, p2, p3, out);
}